// Round 1
// baseline (727.870 us; speedup 1.0000x reference)
//
#include <hip/hip_runtime.h>
#include <cstdint>
#include <cstddef>

namespace {
constexpr int NN     = 8192;
constexpr int DD     = 32;
constexpr int ROWS   = 128;          // rows per attention block
constexpr int TJ     = 64;           // j-tile
constexpr int JSPLIT = 8;            // j-range splits -> 512 blocks
constexpr int JRANGE = NN / JSPLIT;  // 1024
constexpr int WORDS  = NN / 64;      // 128 mask words per row
}

__device__ __forceinline__ float lrelu02(float x) { return fmaxf(x, 0.2f * x); }

// ---------------------------------------------------------------------------
// g = in @ W  (optionally in = ELU(acc/den)),  s_src = g@a[:D], s_dst = g@a[D:]
// ---------------------------------------------------------------------------
template<int DIN, int DOUT, bool FROMACC>
__global__ void k_g(const float* __restrict__ in,
                    const float* __restrict__ den,
                    const float* __restrict__ W,
                    const float* __restrict__ avec,
                    float* __restrict__ g,
                    float* __restrict__ ssrc,
                    float* __restrict__ sdst)
{
  const int i = blockIdx.x * blockDim.x + threadIdx.x;
  float h[DIN];
  if (FROMACC) {
    const float dinv = 1.0f / den[i];
    #pragma unroll
    for (int k = 0; k < DIN; k++) {
      const float v = in[(size_t)i * DIN + k] * dinv;
      h[k] = v > 0.f ? v : (__expf(v) - 1.0f);      // ELU
    }
  } else {
    #pragma unroll
    for (int k = 0; k < DIN; k++) h[k] = in[(size_t)i * DIN + k];
  }
  float ss = 0.f, sd = 0.f;
  #pragma unroll 4
  for (int d = 0; d < DOUT; d++) {
    float a = 0.f;
    #pragma unroll
    for (int k = 0; k < DIN; k++) a += h[k] * W[k * DOUT + d];
    g[(size_t)i * DOUT + d] = a;
    ss += a * avec[d];
    sd += a * avec[DOUT + d];
  }
  ssrc[i] = ss;
  sdst[i] = sd;
}

// ---------------------------------------------------------------------------
// Attention layer (D=32). LAYER==1: reads adj (268 MB stream), emits bitmask.
// LAYER==2: reads bitmask (8 MB, cache-resident).
// Grid: (N/ROWS)*JSPLIT blocks x 256 threads. Unnormalized accumulation with
// atomicAdd combine across j-splits; denominator via per-thread partials.
// ---------------------------------------------------------------------------
template<int LAYER>
__global__ __launch_bounds__(256, 2)
void k_att(const float* __restrict__ adj,
           unsigned long long* __restrict__ mask64,
           const float* __restrict__ g,
           const float* __restrict__ ssrc,
           const float* __restrict__ sdst,
           float* __restrict__ hacc,
           float* __restrict__ den)
{
  __shared__ float gt[TJ][DD];        // 8 KB
  __shared__ float wt[TJ][ROWS + 4];  // stride 132 floats: phase-B b128 conflict-free

  const int t     = threadIdx.x;
  const int bid   = blockIdx.x;
  const int rb    = (bid / JSPLIT) * ROWS;
  const int j0    = (bid % JSPLIT) * JRANGE;
  const int jlane = t & 63;   // phase A: lane = j (coalesced adj, ballot per row)
  const int rgrp  = t >> 6;   // phase A: wave -> 32-row group
  const int cg    = t & 7;    // phase B: 8 col groups x 4 cols
  const int rg    = t >> 3;   // phase B: 32 row groups x 4 rows

  float acc[16];
  #pragma unroll
  for (int i = 0; i < 16; i++) acc[i] = 0.f;
  float dpart[32];
  #pragma unroll
  for (int i = 0; i < 32; i++) dpart[i] = 0.f;

  for (int jt = j0; jt < j0 + JRANGE; jt += TJ) {
    { // stage g tile: 64 j x 32 d, 8 floats/thread, coalesced float4
      const int f  = t * 8;
      const int jj = f >> 5;
      const int d0 = f & 31;
      const float4* src = reinterpret_cast<const float4*>(&g[(size_t)(jt + jj) * DD + d0]);
      float4 v0 = src[0];
      float4 v1 = src[1];
      *reinterpret_cast<float4*>(&gt[jj][d0])     = v0;
      *reinterpret_cast<float4*>(&gt[jj][d0 + 4]) = v1;
    }
    const float sd = sdst[jt + jlane];  // per-lane, coalesced, hoisted over rows

    if constexpr (LAYER == 1) {
      float av[32];
      #pragma unroll
      for (int ii = 0; ii < 32; ii++) {
        const int i = rb + rgrp * 32 + ii;
        av[ii] = adj[(size_t)i * NN + jt + jlane];   // coalesced 256B/wave
      }
      #pragma unroll
      for (int ii = 0; ii < 32; ii++) {
        const int iloc = rgrp * 32 + ii;
        const float sa = ssrc[rb + iloc];            // wave-uniform -> s_load
        const bool m = av[ii] > 0.5f;
        const unsigned long long bal = __ballot(m);
        if (jlane == 0) mask64[(size_t)(rb + iloc) * WORDS + (jt >> 6)] = bal;
        const float w = m ? __expf(lrelu02(sa + sd)) : 0.f;
        wt[jlane][iloc] = w;
        dpart[ii] += w;
      }
    } else {
      #pragma unroll
      for (int ii = 0; ii < 32; ii++) {
        const int iloc = rgrp * 32 + ii;
        const float sa = ssrc[rb + iloc];
        const unsigned long long mw = mask64[(size_t)(rb + iloc) * WORDS + (jt >> 6)]; // uniform
        const bool m = (mw >> jlane) & 1ull;
        const float w = m ? __expf(lrelu02(sa + sd)) : 0.f;
        wt[jlane][iloc] = w;
        dpart[ii] += w;
      }
    }
    __syncthreads();

    // phase B: rank-1 updates; 2x ds_read_b128 + 16 v_fma per thread per jj
    #pragma unroll 8
    for (int jj = 0; jj < TJ; jj++) {
      const float4 wv = *reinterpret_cast<const float4*>(&wt[jj][rg * 4]);
      const float4 gv = *reinterpret_cast<const float4*>(&gt[jj][cg * 4]);
      acc[0]  += wv.x * gv.x;  acc[1]  += wv.x * gv.y;  acc[2]  += wv.x * gv.z;  acc[3]  += wv.x * gv.w;
      acc[4]  += wv.y * gv.x;  acc[5]  += wv.y * gv.y;  acc[6]  += wv.y * gv.z;  acc[7]  += wv.y * gv.w;
      acc[8]  += wv.z * gv.x;  acc[9]  += wv.z * gv.y;  acc[10] += wv.z * gv.z;  acc[11] += wv.z * gv.w;
      acc[12] += wv.w * gv.x;  acc[13] += wv.w * gv.y;  acc[14] += wv.w * gv.z;  acc[15] += wv.w * gv.w;
    }
    __syncthreads();
  }

  #pragma unroll
  for (int r = 0; r < 4; r++) {
    const int i = rb + rg * 4 + r;
    #pragma unroll
    for (int c = 0; c < 4; c++)
      atomicAdd(&hacc[(size_t)i * DD + cg * 4 + c], acc[r * 4 + c]);
  }
  #pragma unroll
  for (int ii = 0; ii < 32; ii++) {
    float v = dpart[ii];
    #pragma unroll
    for (int s = 32; s > 0; s >>= 1) v += __shfl_xor(v, s, 64);
    if (jlane == 0) atomicAdd(&den[rb + rgrp * 32 + ii], v);
  }
}

// ---------------------------------------------------------------------------
// Layer 3: only row 0 of the attention output is needed. 32 blocks x 256 j.
// ---------------------------------------------------------------------------
__global__ void k_att3(const unsigned long long* __restrict__ mask64,
                       const float* __restrict__ g3,
                       const float* __restrict__ ssrc,
                       const float* __restrict__ sdst,
                       float* __restrict__ o3,
                       float* __restrict__ den3)
{
  __shared__ float wl[256];
  const int t = threadIdx.x;
  const int jb = blockIdx.x * 256;
  const int j = jb + t;
  const unsigned long long mw = mask64[j >> 6];  // row 0 of mask
  const bool m = (mw >> (j & 63)) & 1ull;
  const float e = ssrc[0] + sdst[j];
  const float w = m ? __expf(fmaxf(e, 0.2f * e)) : 0.f;
  wl[t] = w;
  float v = w;
  #pragma unroll
  for (int s = 32; s > 0; s >>= 1) v += __shfl_xor(v, s, 64);
  if ((t & 63) == 0) atomicAdd(den3, v);
  __syncthreads();
  for (int idx = t; idx < 33 * 8; idx += 256) {
    const int d = idx % 33;
    const int oct = idx / 33;
    float s = 0.f;
    for (int jj = 0; jj < 32; jj++)
      s += wl[oct * 32 + jj] * g3[(size_t)(jb + oct * 32 + jj) * 33 + d];
    atomicAdd(&o3[d], s);
  }
}

// ---------------------------------------------------------------------------
// Final MLP on node 0 (leaky slope 0.01; layer-3 GAT output has NO ELU)
// ---------------------------------------------------------------------------
__global__ void k_mlp(const float* __restrict__ o3, const float* __restrict__ den3,
                      const float* __restrict__ Wm1, const float* __restrict__ bm1,
                      const float* __restrict__ Wm2, const float* __restrict__ bm2,
                      float* __restrict__ out)
{
  __shared__ float h0[33];
  __shared__ float hid[128];
  const int t = threadIdx.x;  // 128 threads
  if (t < 33) h0[t] = o3[t] / den3[0];
  __syncthreads();
  float a = bm1[t];
  for (int k = 0; k < 33; k++) a += h0[k] * Wm1[k * 128 + t];
  hid[t] = fmaxf(a, 0.01f * a);
  __syncthreads();
  if (t < 27) {
    float o = bm2[t];
    for (int k = 0; k < 128; k++) o += hid[k] * Wm2[k * 27 + t];
    out[t] = o;
  }
}

extern "C" void kernel_launch(void* const* d_in, const int* in_sizes, int n_in,
                              void* d_out, int out_size, void* d_ws, size_t ws_size,
                              hipStream_t stream)
{
  const float* x   = (const float*)d_in[0];
  const float* adj = (const float*)d_in[1];
  const float* W1  = (const float*)d_in[2];
  const float* a1  = (const float*)d_in[3];
  const float* W2  = (const float*)d_in[4];
  const float* a2  = (const float*)d_in[5];
  const float* W3  = (const float*)d_in[6];
  const float* a3  = (const float*)d_in[7];
  const float* Wm1 = (const float*)d_in[8];
  const float* bm1 = (const float*)d_in[9];
  const float* Wm2 = (const float*)d_in[10];
  const float* bm2 = (const float*)d_in[11];
  float* out = (float*)d_out;
  (void)in_sizes; (void)n_in; (void)out_size; (void)ws_size;

  char* ws = (char*)d_ws;
  size_t off = 0;
  auto alloc = [&](size_t bytes) -> void* {
    void* p = ws + off;
    off = (off + bytes + 255) & ~(size_t)255;
    return p;
  };
  float* g1  = (float*)alloc((size_t)NN * 32 * 4);
  float* g2  = (float*)alloc((size_t)NN * 32 * 4);
  float* g3  = (float*)alloc((size_t)NN * 33 * 4);
  float* s1s = (float*)alloc((size_t)NN * 4);
  float* s1d = (float*)alloc((size_t)NN * 4);
  float* s2s = (float*)alloc((size_t)NN * 4);
  float* s2d = (float*)alloc((size_t)NN * 4);
  float* s3s = (float*)alloc((size_t)NN * 4);
  float* s3d = (float*)alloc((size_t)NN * 4);
  char* zbase = ws + off;                     // contiguous zero-init region
  float* h1acc = (float*)alloc((size_t)NN * 32 * 4);
  float* den1  = (float*)alloc((size_t)NN * 4);
  float* h2acc = (float*)alloc((size_t)NN * 32 * 4);
  float* den2  = (float*)alloc((size_t)NN * 4);
  float* o3    = (float*)alloc(64 * 4);
  float* den3  = (float*)alloc(64 * 4);
  const size_t zbytes = (size_t)((ws + off) - zbase);
  unsigned long long* mask64 = (unsigned long long*)alloc((size_t)NN * WORDS * 8);

  hipMemsetAsync(zbase, 0, zbytes, stream);
  k_g<33, 32, false><<<NN / 256, 256, 0, stream>>>(x, nullptr, W1, a1, g1, s1s, s1d);
  k_att<1><<<(NN / ROWS) * JSPLIT, 256, 0, stream>>>(adj, mask64, g1, s1s, s1d, h1acc, den1);
  k_g<32, 32, true><<<NN / 256, 256, 0, stream>>>(h1acc, den1, W2, a2, g2, s2s, s2d);
  k_att<2><<<(NN / ROWS) * JSPLIT, 256, 0, stream>>>(nullptr, mask64, g2, s2s, s2d, h2acc, den2);
  k_g<32, 33, true><<<NN / 256, 256, 0, stream>>>(h2acc, den2, W3, a3, g3, s3s, s3d);
  k_att3<<<NN / 256, 256, 0, stream>>>(mask64, g3, s3s, s3d, o3, den3);
  k_mlp<<<1, 128, 0, stream>>>(o3, den3, Wm1, bm1, Wm2, bm2, out);
}

// Round 2
// 535.083 us; speedup vs baseline: 1.3603x; 1.3603x over previous
//
#include <hip/hip_runtime.h>
#include <cstdint>
#include <cstddef>

namespace {
constexpr int NN     = 8192;
constexpr int DD     = 32;
constexpr int ROWS   = 128;          // rows per attention block
constexpr int TJ     = 64;           // j-tile (K per MFMA round = 64)
constexpr int JSPLIT = 16;           // j-range splits -> 1024 blocks (4/CU)
constexpr int JRANGE = NN / JSPLIT;  // 512
constexpr int WORDS  = NN / 64;      // 128 mask words per row
constexpr int STR    = 72;           // LDS row stride in halfwords (144 B, 16B-aligned)
}

typedef __attribute__((ext_vector_type(8))) short short8;
typedef __attribute__((ext_vector_type(4))) float floatx4;

__device__ __forceinline__ unsigned short f2bf(float f) {
  unsigned int u = __float_as_uint(f);
  u += 0x7fffu + ((u >> 16) & 1u);          // RNE
  return (unsigned short)(u >> 16);
}

// ---------------------------------------------------------------------------
// g = in @ W (optionally in = ELU(acc/den)); s_src = g@a[:D]; s_dst = g@a[D:]
// W cached in LDS (broadcast reads). Optional outputs: fp32 g (layer 3),
// bf16 transposed gT[d][node] (layers 1/2, coalesced per-d stores).
// ---------------------------------------------------------------------------
template<int DIN, int DOUT, bool FROMACC>
__global__ void k_g(const float* __restrict__ in,
                    const float* __restrict__ den,
                    const float* __restrict__ W,
                    const float* __restrict__ avec,
                    float* __restrict__ g,
                    unsigned short* __restrict__ gT,
                    float* __restrict__ ssrc,
                    float* __restrict__ sdst)
{
  __shared__ float Ws[DIN * DOUT];
  __shared__ float as[2 * DOUT];
  const int t = threadIdx.x;  // 128
  for (int idx = t; idx < DIN * DOUT; idx += 128) Ws[idx] = W[idx];
  if (t < 2 * DOUT) as[t] = avec[t];
  __syncthreads();

  const int i = blockIdx.x * 128 + t;
  float h[DIN];
  if (FROMACC) {
    const float dinv = 1.0f / den[i];
    #pragma unroll
    for (int k = 0; k < DIN; k++) {
      const float v = in[(size_t)i * DIN + k] * dinv;
      h[k] = v > 0.f ? v : (__expf(v) - 1.0f);      // ELU
    }
  } else {
    #pragma unroll
    for (int k = 0; k < DIN; k++) h[k] = in[(size_t)i * DIN + k];
  }
  float ss = 0.f, sd = 0.f;
  #pragma unroll 4
  for (int d = 0; d < DOUT; d++) {
    float a = 0.f;
    #pragma unroll
    for (int k = 0; k < DIN; k++) a += h[k] * Ws[k * DOUT + d];
    if (g)  g[(size_t)i * DOUT + d] = a;
    if (gT) gT[(size_t)d * NN + i] = f2bf(a);       // coalesced in i
    ss += a * as[d];
    sd += a * as[DOUT + d];
  }
  ssrc[i] = ss;
  sdst[i] = sd;
}

// ---------------------------------------------------------------------------
// Attention layer (D=32) via bf16 MFMA. LAYER==1: streams adj (268 MB),
// emits bitmask. LAYER==2: reads 8 MB bitmask (cache-resident).
// Block = 128 rows x JRANGE cols, 256 thr; per j-tile of 64:
//   phase A: w = mask ? exp(lrelu(s_i+s_j)) : 0 -> bf16 -> wt[row][j] (LDS)
//   phase B: H += W x G via mfma_16x16x32_bf16; den via ones-B-fragment MFMA
//            (num and den use IDENTICAL bf16 weights -> rounding cancels).
// ---------------------------------------------------------------------------
template<int LAYER>
__global__ __launch_bounds__(256, 4)
void k_att(const float* __restrict__ adj,
           unsigned long long* __restrict__ mask64,
           const unsigned short* __restrict__ gT,
           const float* __restrict__ ssrc,
           const float* __restrict__ sdst,
           float* __restrict__ hacc,
           float* __restrict__ den)
{
  __shared__ unsigned short wt[ROWS * STR];  // [row][j] bf16, 18.0 KB
  __shared__ unsigned short gt[DD * STR];    // [d][j]  bf16 (transposed), 4.5 KB

  const int t    = threadIdx.x;
  const int lane = t & 63;
  const int wv   = __builtin_amdgcn_readfirstlane(t >> 6);
  const int quad = lane >> 4;
  const int m16  = lane & 15;
  const int rb   = (blockIdx.x / JSPLIT) * ROWS;
  const int j0   = (blockIdx.x % JSPLIT) * JRANGE;
  const int r0   = wv * 32;                  // this wave's 32 rows

  floatx4 acc[2][2];
  floatx4 dacc[2];
  #pragma unroll
  for (int a = 0; a < 2; a++) {
    dacc[a] = (floatx4){0.f, 0.f, 0.f, 0.f};
    #pragma unroll
    for (int b = 0; b < 2; b++) acc[a][b] = (floatx4){0.f, 0.f, 0.f, 0.f};
  }
  short8 ones;
  #pragma unroll
  for (int k = 0; k < 8; k++) ones[k] = (short)0x3F80;  // bf16 1.0

  const int sdrow = t >> 3;         // gt staging: d row 0..31
  const int soff  = (t & 7) * 8;    // j offset 0..56

  for (int jt = j0; jt < j0 + JRANGE; jt += TJ) {
    // global loads first: g-tile slice + per-lane s_dst (latency overlaps phase A)
    const short8 gvld = *reinterpret_cast<const short8*>(&gT[(size_t)sdrow * NN + jt + soff]);
    const float sdj = sdst[jt + lane];

    // ---- phase A: weights for this wave's 32 rows ----
    if constexpr (LAYER == 1) {
      float av[32];
      #pragma unroll
      for (int ii = 0; ii < 32; ii++)
        av[ii] = adj[(size_t)(rb + r0 + ii) * NN + jt + lane];   // 256B/wave coalesced
      #pragma unroll
      for (int ii = 0; ii < 32; ii++) {
        const int iu = rb + r0 + ii;
        const float sa = ssrc[iu];                               // uniform -> s_load
        const bool m = av[ii] > 0.5f;
        const unsigned long long bal = __ballot(m);
        if (lane == 0) mask64[(size_t)iu * WORDS + (jt >> 6)] = bal;
        const float e = sa + sdj;
        const float w = m ? __expf(fmaxf(e, 0.2f * e)) : 0.f;
        wt[(r0 + ii) * STR + lane] = f2bf(w);                    // conflict-free b16
      }
    } else {
      #pragma unroll
      for (int ii = 0; ii < 32; ii++) {
        const int iu = rb + r0 + ii;
        const float sa = ssrc[iu];
        const unsigned long long mw = mask64[(size_t)iu * WORDS + (jt >> 6)]; // uniform
        const bool m = (mw >> lane) & 1ull;
        const float e = sa + sdj;
        const float w = m ? __expf(fmaxf(e, 0.2f * e)) : 0.f;
        wt[(r0 + ii) * STR + lane] = f2bf(w);
      }
    }
    // stage g tile (written after prev phase B finished via loop-end barrier)
    *reinterpret_cast<short8*>(&gt[sdrow * STR + soff]) = gvld;
    __syncthreads();

    // ---- phase B: MFMA. A = wt rows (m=lane&15), B = gt cols (n=lane&15) ----
    #pragma unroll
    for (int ks = 0; ks < 2; ks++) {
      const int ko = ks * 32 + quad * 8;
      const short8 bf0 = *reinterpret_cast<const short8*>(&gt[m16 * STR + ko]);
      const short8 bf1 = *reinterpret_cast<const short8*>(&gt[(16 + m16) * STR + ko]);
      #pragma unroll
      for (int mt = 0; mt < 2; mt++) {
        const short8 af = *reinterpret_cast<const short8*>(&wt[(r0 + mt * 16 + m16) * STR + ko]);
        acc[mt][0] = __builtin_amdgcn_mfma_f32_16x16x32_bf16(af, bf0, acc[mt][0], 0, 0, 0);
        acc[mt][1] = __builtin_amdgcn_mfma_f32_16x16x32_bf16(af, bf1, acc[mt][1], 0, 0, 0);
        dacc[mt]   = __builtin_amdgcn_mfma_f32_16x16x32_bf16(af, ones, dacc[mt], 0, 0, 0);
      }
    }
    __syncthreads();
  }

  // epilogue: C/D layout col=lane&15, row=quad*4+reg [HW-verified]
  #pragma unroll
  for (int mt = 0; mt < 2; mt++) {
    const int rr = rb + r0 + mt * 16 + quad * 4;
    #pragma unroll
    for (int r = 0; r < 4; r++) {
      atomicAdd(&hacc[(size_t)(rr + r) * DD + m16],      acc[mt][0][r]);
      atomicAdd(&hacc[(size_t)(rr + r) * DD + 16 + m16], acc[mt][1][r]);
    }
    if (m16 == 0) {
      #pragma unroll
      for (int r = 0; r < 4; r++) atomicAdd(&den[rr + r], dacc[mt][r]);
    }
  }
}

// ---------------------------------------------------------------------------
// Layer 3: only row 0 of the attention output is needed (fp32 exact).
// ---------------------------------------------------------------------------
__global__ void k_att3(const unsigned long long* __restrict__ mask64,
                       const float* __restrict__ g3,
                       const float* __restrict__ ssrc,
                       const float* __restrict__ sdst,
                       float* __restrict__ o3,
                       float* __restrict__ den3)
{
  __shared__ float wl[256];
  const int t = threadIdx.x;
  const int jb = blockIdx.x * 256;
  const int j = jb + t;
  const unsigned long long mw = mask64[j >> 6];  // row 0 of mask
  const bool m = (mw >> (j & 63)) & 1ull;
  const float e = ssrc[0] + sdst[j];
  const float w = m ? __expf(fmaxf(e, 0.2f * e)) : 0.f;
  wl[t] = w;
  float v = w;
  #pragma unroll
  for (int s = 32; s > 0; s >>= 1) v += __shfl_xor(v, s, 64);
  if ((t & 63) == 0) atomicAdd(den3, v);
  __syncthreads();
  for (int idx = t; idx < 33 * 8; idx += 256) {
    const int d = idx % 33;
    const int oct = idx / 33;
    float s = 0.f;
    for (int jj = 0; jj < 32; jj++)
      s += wl[oct * 32 + jj] * g3[(size_t)(jb + oct * 32 + jj) * 33 + d];
    atomicAdd(&o3[d], s);
  }
}

// ---------------------------------------------------------------------------
// Final MLP on node 0 (leaky slope 0.01; layer-3 GAT output has NO ELU)
// ---------------------------------------------------------------------------
__global__ void k_mlp(const float* __restrict__ o3, const float* __restrict__ den3,
                      const float* __restrict__ Wm1, const float* __restrict__ bm1,
                      const float* __restrict__ Wm2, const float* __restrict__ bm2,
                      float* __restrict__ out)
{
  __shared__ float h0[33];
  __shared__ float hid[128];
  const int t = threadIdx.x;  // 128 threads
  if (t < 33) h0[t] = o3[t] / den3[0];
  __syncthreads();
  float a = bm1[t];
  for (int k = 0; k < 33; k++) a += h0[k] * Wm1[k * 128 + t];
  hid[t] = fmaxf(a, 0.01f * a);
  __syncthreads();
  if (t < 27) {
    float o = bm2[t];
    for (int k = 0; k < 128; k++) o += hid[k] * Wm2[k * 27 + t];
    out[t] = o;
  }
}

extern "C" void kernel_launch(void* const* d_in, const int* in_sizes, int n_in,
                              void* d_out, int out_size, void* d_ws, size_t ws_size,
                              hipStream_t stream)
{
  const float* x   = (const float*)d_in[0];
  const float* adj = (const float*)d_in[1];
  const float* W1  = (const float*)d_in[2];
  const float* a1  = (const float*)d_in[3];
  const float* W2  = (const float*)d_in[4];
  const float* a2  = (const float*)d_in[5];
  const float* W3  = (const float*)d_in[6];
  const float* a3  = (const float*)d_in[7];
  const float* Wm1 = (const float*)d_in[8];
  const float* bm1 = (const float*)d_in[9];
  const float* Wm2 = (const float*)d_in[10];
  const float* bm2 = (const float*)d_in[11];
  float* out = (float*)d_out;
  (void)in_sizes; (void)n_in; (void)out_size; (void)ws_size;

  char* ws = (char*)d_ws;
  size_t off = 0;
  auto alloc = [&](size_t bytes) -> void* {
    void* p = ws + off;
    off = (off + bytes + 255) & ~(size_t)255;
    return p;
  };
  float* g3  = (float*)alloc((size_t)NN * 33 * 4);
  float* s1s = (float*)alloc((size_t)NN * 4);
  float* s1d = (float*)alloc((size_t)NN * 4);
  float* s2s = (float*)alloc((size_t)NN * 4);
  float* s2d = (float*)alloc((size_t)NN * 4);
  float* s3s = (float*)alloc((size_t)NN * 4);
  float* s3d = (float*)alloc((size_t)NN * 4);
  char* zbase = ws + off;                     // contiguous zero-init region
  float* h1acc = (float*)alloc((size_t)NN * DD * 4);
  float* den1  = (float*)alloc((size_t)NN * 4);
  float* h2acc = (float*)alloc((size_t)NN * DD * 4);
  float* den2  = (float*)alloc((size_t)NN * 4);
  float* o3    = (float*)alloc(64 * 4);
  float* den3  = (float*)alloc(64 * 4);
  const size_t zbytes = (size_t)((ws + off) - zbase);
  unsigned long long* mask64 = (unsigned long long*)alloc((size_t)NN * WORDS * 8);
  unsigned short* g1T = (unsigned short*)alloc((size_t)DD * NN * 2);
  unsigned short* g2T = (unsigned short*)alloc((size_t)DD * NN * 2);

  hipMemsetAsync(zbase, 0, zbytes, stream);
  k_g<33, 32, false><<<NN / 128, 128, 0, stream>>>(x, nullptr, W1, a1, nullptr, g1T, s1s, s1d);
  k_att<1><<<(NN / ROWS) * JSPLIT, 256, 0, stream>>>(adj, mask64, g1T, s1s, s1d, h1acc, den1);
  k_g<32, 32, true><<<NN / 128, 128, 0, stream>>>(h1acc, den1, W2, a2, nullptr, g2T, s2s, s2d);
  k_att<2><<<(NN / ROWS) * JSPLIT, 256, 0, stream>>>(nullptr, mask64, g2T, s2s, s2d, h2acc, den2);
  k_g<32, 33, true><<<NN / 128, 128, 0, stream>>>(h2acc, den2, W3, a3, g3, nullptr, s3s, s3d);
  k_att3<<<NN / 256, 256, 0, stream>>>(mask64, g3, s3s, s3d, o3, den3);
  k_mlp<<<1, 128, 0, stream>>>(o3, den3, Wm1, bm1, Wm2, bm2, out);
}